// Round 10
// baseline (203.519 us; speedup 1.0000x reference)
//
#include <hip/hip_runtime.h>

// ---------------------------------------------------------------------------
// CovariateAttention: out = MHA_causal(rope(x@Wq^T), rope(x@Wk^T), x@Wv^T) @ Wo^T
// B=2, S=2048, E=d_attn=1024, H=16, hd=64. All GEMM-shaped work in bf16 MFMA.
// 4 launches: cvt -> gemm0(QKV + fused RoPE, BN=64) -> attnk -> gemm2.
// ---------------------------------------------------------------------------

typedef float  f32x4  __attribute__((ext_vector_type(4)));
typedef short  short8 __attribute__((ext_vector_type(8)));

#define MFMA16(a,b,c) __builtin_amdgcn_mfma_f32_16x16x32_bf16((a),(b),(c),0,0,0)
// async global->LDS DMA, 16B/lane; LDS dest = wave-uniform base + lane*16
#define GLD_LDS16(g, l)                                                        \
  __builtin_amdgcn_global_load_lds(                                            \
      (const __attribute__((address_space(1))) unsigned int*)(g),              \
      (__attribute__((address_space(3))) unsigned int*)(l), 16, 0, 0)

__device__ __forceinline__ unsigned short f2bf(float f) {
  unsigned int x = __float_as_uint(f);
  x += 0x7fffu + ((x >> 16) & 1u);          // RNE
  return (unsigned short)(x >> 16);
}
__device__ __forceinline__ float bf2f(unsigned short u) {
  return __uint_as_float(((unsigned int)u) << 16);
}

// ---------------------------------------------------------------------------
// Kernel 1: convert x (4M fp32) + Wq,Wk,Wv,Wo (1M each) to bf16 (contiguous).
// ---------------------------------------------------------------------------
__global__ __launch_bounds__(256) void cvt_all(const float* __restrict__ x,
                                               const float* __restrict__ wq,
                                               const float* __restrict__ wk,
                                               const float* __restrict__ wv,
                                               const float* __restrict__ wo,
                                               ushort* __restrict__ dst) {
  const int i = blockIdx.x * 256 + threadIdx.x;      // [0, 2M)
  const float* src;
  int off;
  if (i < 1048576) { src = x; off = i; }
  else {
    const int j = i - 1048576;
    const int wsel = j >> 18;
    off = j & 262143;
    src = (wsel == 0) ? wq : (wsel == 1) ? wk : (wsel == 2) ? wv : wo;
  }
  const float4 v = ((const float4*)src)[off];
  ushort4 o = make_ushort4(f2bf(v.x), f2bf(v.y), f2bf(v.z), f2bf(v.w));
  ((ushort4*)dst)[i] = o;
}

// ---------------------------------------------------------------------------
// GEMM (m97 pattern + cross-round LDS DOUBLE BUFFER): C[m,n]=sum_k A[m,k]*B[n,k].
// BM=128 x BN tile, BK=32, 256 thr = 4 waves (2x2), wave tile 64 x BN/2.
// Round k: barrier (drains buf_cur's DMA, issued a full compute-phase ago),
// issue buf_next GLD16, compute from buf_cur. Load latency overlapped with
// compute INSIDE each block — the m97 same-round drain was the stall at this
// short-K latency-bound shape. LDS 24 KB (dbuf at BK=64 would be 48 KB and
// halve 6 blocks/CU — the r7 mistake).
// MODE 0 (BN=64): fused QKV, N=3072, 1536 blocks = 6/CU. Q/K get RoPE in the
//   epilogue (pair partner d^1 in adjacent lane -> __shfl_xor(.,1); hw sincos
//   in revolutions). Q scaled by attn_scale*log2e. V pre-transposed [bh][d][s].
// MODE 2 (BN=64): fp32 row-major output (out-proj), 512 blocks.
// ---------------------------------------------------------------------------
template<int MODE, int BN>
__global__ __launch_bounds__(256) void gemm_bt(const ushort* __restrict__ A,
                                               const ushort* __restrict__ B,
                                               void* __restrict__ Cv,
                                               int K) {
  constexpr int NI = BN / 32;               // n-frags per wave (4 or 2)
  __shared__ __align__(16) short As[2][128 * 32];
  __shared__ __align__(16) short Bs[2][BN * 32];
  const int tid  = threadIdx.x;
  const int lane = tid & 63, w = tid >> 6;
  const int ln   = lane & 15, quad = lane >> 4;
  const int wm   = w >> 1, wn = w & 1;
  const int m0 = blockIdx.y * 128, n0 = blockIdx.x * BN;

  const int srow = lane >> 2;               // 0..15
  const int schk = (lane & 3) * 8;          // 0,8,16,24 (shorts)
  const ushort* Ag0 = A + (size_t)(m0 + w * 32      + srow) * K + schk;
  const ushort* Ag1 = A + (size_t)(m0 + w * 32 + 16 + srow) * K + schk;
  const int brow = (BN == 128) ? w * 32 : w * 16;
  const ushort* Bg0 = B + (size_t)(n0 + brow + srow) * K + schk;
  const ushort* Bg1 = B + (size_t)(n0 + brow + 16 + srow) * K + schk; // BN==128 only
  const int lA0 = (w * 32) * 32, lA1 = (w * 32 + 16) * 32;
  const int lB0 = brow * 32,     lB1 = (brow + 16) * 32;

  int aoff[4], boff[NI];
#pragma unroll
  for (int i = 0; i < 4; i++)
    aoff[i] = (wm * 64 + i * 16 + ln) * 32 + quad * 8;
#pragma unroll
  for (int i = 0; i < NI; i++)
    boff[i] = (wn * (BN / 2) + i * 16 + ln) * 32 + quad * 8;
  f32x4 acc[4][NI] = {};

  // prologue: stage round 0 into buffer 0
  GLD_LDS16(Ag0, &As[0][lA0]);
  GLD_LDS16(Ag1, &As[0][lA1]);
  GLD_LDS16(Bg0, &Bs[0][lB0]);
  if (BN == 128) GLD_LDS16(Bg1, &Bs[0][lB1]);

  for (int kt = 0; kt < K; kt += 32) {
    const int cur = (kt >> 5) & 1, nxt = cur ^ 1;
    __syncthreads();   // drains buf_cur DMA (in flight for a full round) +
                       // WAR: everyone's reads of buf_nxt (2 rounds ago) done
    if (kt + 32 < K) {
      GLD_LDS16(Ag0 + kt + 32, &As[nxt][lA0]);
      GLD_LDS16(Ag1 + kt + 32, &As[nxt][lA1]);
      GLD_LDS16(Bg0 + kt + 32, &Bs[nxt][lB0]);
      if (BN == 128) GLD_LDS16(Bg1 + kt + 32, &Bs[nxt][lB1]);
    }
    short8 av[4], bv[NI];
#pragma unroll
    for (int i = 0; i < 4; i++) av[i] = *(const short8*)&As[cur][aoff[i]];
#pragma unroll
    for (int i = 0; i < NI; i++) bv[i] = *(const short8*)&Bs[cur][boff[i]];
#pragma unroll
    for (int mi = 0; mi < 4; mi++)
#pragma unroll
      for (int ni = 0; ni < NI; ni++)
        acc[mi][ni] = MFMA16(av[mi], bv[ni], acc[mi][ni]);
  }

  // Epilogue. C-layout: row = quad*4 + r, col = ln (verified m89/m91).
  if (MODE == 0) {
    ushort* Cq = (ushort*)Cv;
    if (n0 < 2048) {
      // ---- Q/K with fused RoPE ----
      ushort* dst = Cq + (n0 < 1024 ? 0 : 4194304);   // q or k buffer
      const int nbase = (n0 < 1024) ? n0 : n0 - 1024;
      const float qsc = (n0 < 1024) ? 0.04508422002778011f : 1.0f; // (1/32)*log2e
      const float sgn = (ln & 1) ? 1.0f : -1.0f;       // odd lane: +other*sn
      float invc[NI];                                  // invf * 1/(2*pi)
#pragma unroll
      for (int ni = 0; ni < NI; ni++) {
        // pair index within the head = (col & 63) >> 1, BN-generic
        const int ii = ((wn * (BN / 2) + ni * 16 + ln) & 63) >> 1;
        invc[ni] = __builtin_amdgcn_exp2f(-(float)ii * 0.4152410118579865f) *
                   0.15915494309189535f;
      }
#pragma unroll
      for (int mi = 0; mi < 4; mi++) {
        const int row = m0 + wm * 64 + mi * 16 + quad * 4;
#pragma unroll
        for (int ni = 0; ni < NI; ni++) {
          const int col = nbase + wn * (BN / 2) + ni * 16 + ln;
#pragma unroll
          for (int r = 0; r < 4; r++) {
            const float mine  = acc[mi][ni][r];
            const float other = __shfl_xor(mine, 1, 64);
            const int   s     = (row + r) & 2047;      // sequence position
            const float rev   = (float)s * invc[ni];
            const float rr    = rev - floorf(rev);
            const float sn = __builtin_amdgcn_sinf(rr);
            const float cs = __builtin_amdgcn_cosf(rr);
            const float rot = (mine * cs + sgn * other * sn) * qsc;
            dst[(size_t)(row + r) * 1024 + col] = f2bf(rot);
          }
        }
      }
    } else {
      // ---- V pre-transposed to [bh][d][s] (no rope) ----
      ushort* vt = Cq + 8388608;
#pragma unroll
      for (int mi = 0; mi < 4; mi++) {
        const int sm = m0 + wm * 64 + mi * 16 + quad * 4;   // token index
        const int b = sm >> 11, s = sm & 2047;
#pragma unroll
        for (int ni = 0; ni < NI; ni++) {
          const int nv = (n0 - 2048) + wn * (BN / 2) + ni * 16 + ln;
          const int bh = b * 16 + (nv >> 6), d = nv & 63;
          ushort4 u = make_ushort4(f2bf(acc[mi][ni][0]), f2bf(acc[mi][ni][1]),
                                   f2bf(acc[mi][ni][2]), f2bf(acc[mi][ni][3]));
          *(ushort4*)&vt[((size_t)bh * 64 + d) * 2048 + s] = u;
        }
      }
    }
  } else {
    float* C = (float*)Cv;
#pragma unroll
    for (int mi = 0; mi < 4; mi++) {
      const int row = m0 + wm * 64 + mi * 16 + quad * 4;
#pragma unroll
      for (int ni = 0; ni < NI; ni++) {
        const int col = n0 + wn * (BN / 2) + ni * 16 + ln;
#pragma unroll
        for (int r = 0; r < 4; r++)
          C[(size_t)(row + r) * 1024 + col] = acc[mi][ni][r];
      }
    }
  }
}

// ---------------------------------------------------------------------------
// Kernel 4 (r4-exact, measured 54.4-61.5us): causal-balanced flash attention,
// max-free softmax. Block x in [0,16) owns q-tiles jA=x (KV 0..x) and
// jB=31-x (KV 0..31-x): 33 tile-equivs, uniform. 256 thr = 4 waves; wave w
// owns rows [16w,16w+16) of each q-tile. Scores s' = qk*attn_scale*log2e are
// bounded (|s'|<~2.5) -> p=exp2(s') direct, no running max, no rescale;
// l as per-lane partials reduced once at the end. VGPR~100 (NO launch-bounds
// pin, NO 2-tile rounds — rounds 5 & 7 both regressed when perturbing this).
// LDS 27648 B.
// ---------------------------------------------------------------------------
__global__ __launch_bounds__(256) void attnk(const ushort* __restrict__ q,
                                             const ushort* __restrict__ k,
                                             const ushort* __restrict__ vt,
                                             ushort* __restrict__ ctx) {
  __shared__ __align__(16) short Ks[64 * 72];
  __shared__ __align__(16) short Vs[64 * 72];
  __shared__ __align__(16) short Ps[4 * 16 * 72];
  const int tid  = threadIdx.x;
  const int lane = tid & 63, w = tid >> 6;
  const int ln   = lane & 15, quad = lane >> 4;
  const int x = blockIdx.x, bh = blockIdx.y;
  const int b = bh >> 4, h = bh & 15;
  const int jA = x, jB = 31 - x;
  short* Pw = Ps + w * 1152;

  // Q fragments (A-layout: m=ln, k=quad*8+j)
  const size_t qbA = ((size_t)(b * 2048 + jA * 64 + w * 16 + ln)) * 1024 + h * 64;
  const size_t qbB = ((size_t)(b * 2048 + jB * 64 + w * 16 + ln)) * 1024 + h * 64;
  const short8 aqA0 = *(const short8*)&q[qbA + quad * 8];
  const short8 aqA1 = *(const short8*)&q[qbA + 32 + quad * 8];
  const short8 aqB0 = *(const short8*)&q[qbB + quad * 8];
  const short8 aqB1 = *(const short8*)&q[qbB + 32 + quad * 8];

  f32x4 oA[4] = {}, oB[4] = {};
  float lsA[4] = {0.f, 0.f, 0.f, 0.f}, lsB[4] = {0.f, 0.f, 0.f, 0.f};

  // staging: 256 threads cover 64x64 tile as 512 short8 slots
  const int s0 = tid, s1 = tid + 256;
  const int r0 = s0 >> 3, c0 = (s0 & 7) * 8;
  const int r1 = s1 >> 3, c1 = (s1 & 7) * 8;
  const ushort* kg0 = k  + ((size_t)(b * 2048 + r0)) * 1024 + h * 64 + c0;
  const ushort* kg1 = k  + ((size_t)(b * 2048 + r1)) * 1024 + h * 64 + c1;
  const ushort* vg0 = vt + ((size_t)(bh * 64 + r0)) * 2048 + c0;
  const ushort* vg1 = vt + ((size_t)(bh * 64 + r1)) * 2048 + c1;
  const int wK0 = r0 * 72 + c0, wK1 = r1 * 72 + c1;

  for (int t = 0; t <= jB; t++) {
    __syncthreads();                      // WAR vs previous compute
    *(short8*)&Ks[wK0] = *(const short8*)(kg0 + (size_t)t * 65536);
    *(short8*)&Ks[wK1] = *(const short8*)(kg1 + (size_t)t * 65536);
    *(short8*)&Vs[wK0] = *(const short8*)(vg0 + t * 64);
    *(short8*)&Vs[wK1] = *(const short8*)(vg1 + t * 64);
    __syncthreads();                      // RAW

    const bool actA = (t <= jA);          // block-uniform
    f32x4 scA[4], scB[4];
#pragma unroll
    for (int ct = 0; ct < 4; ct++) {
      const short8 bk0 = *(const short8*)&Ks[(ct * 16 + ln) * 72 + quad * 8];
      const short8 bk1 = *(const short8*)&Ks[(ct * 16 + ln) * 72 + 32 + quad * 8];
      f32x4 z = {0.f, 0.f, 0.f, 0.f};
      z = MFMA16(aqB0, bk0, z);
      z = MFMA16(aqB1, bk1, z);
      scB[ct] = z;
      if (actA) {
        f32x4 y = {0.f, 0.f, 0.f, 0.f};
        y = MFMA16(aqA0, bk0, y);
        y = MFMA16(aqA1, bk1, y);
        scA[ct] = y;
      }
    }
    if (t == jB) {                        // diag mask for tile B
#pragma unroll
      for (int ct = 0; ct < 4; ct++) {
        const int kv = (t << 6) + ct * 16 + ln;
#pragma unroll
        for (int r = 0; r < 4; r++)
          if (kv > jB * 64 + w * 16 + quad * 4 + r) scB[ct][r] = -100000.0f;
      }
    }
    if (actA && t == jA) {                // diag mask for tile A
#pragma unroll
      for (int ct = 0; ct < 4; ct++) {
        const int kv = (t << 6) + ct * 16 + ln;
#pragma unroll
        for (int r = 0; r < 4; r++)
          if (kv > jA * 64 + w * 16 + quad * 4 + r) scA[ct][r] = -100000.0f;
      }
    }

    // V fragments once, shared by both q-tiles
    short8 bv0[4], bv1[4];
#pragma unroll
    for (int dt = 0; dt < 4; dt++) {
      bv0[dt] = *(const short8*)&Vs[(dt * 16 + ln) * 72 + quad * 8];
      bv1[dt] = *(const short8*)&Vs[(dt * 16 + ln) * 72 + 32 + quad * 8];
    }

    // ---- tile B: p = exp2(s'), accumulate directly (no rescale) ----
#pragma unroll
    for (int ct = 0; ct < 4; ct++)
#pragma unroll
      for (int r = 0; r < 4; r++) {
        const float p = __builtin_amdgcn_exp2f(scB[ct][r]);
        lsB[r] += p;
        Pw[(quad * 4 + r) * 72 + ct * 16 + ln] = (short)f2bf(p);
      }
    {
      const short8 ap0 = *(const short8*)&Pw[ln * 72 + quad * 8];
      const short8 ap1 = *(const short8*)&Pw[ln * 72 + 32 + quad * 8];
#pragma unroll
      for (int dt = 0; dt < 4; dt++) {
        oB[dt] = MFMA16(ap0, bv0[dt], oB[dt]);
        oB[dt] = MFMA16(ap1, bv1[dt], oB[dt]);
      }
    }
    // ---- tile A (reuses Pw; same-wave LDS ops are ordered) ----
    if (actA) {
#pragma unroll
      for (int ct = 0; ct < 4; ct++)
#pragma unroll
        for (int r = 0; r < 4; r++) {
          const float p = __builtin_amdgcn_exp2f(scA[ct][r]);
          lsA[r] += p;
          Pw[(quad * 4 + r) * 72 + ct * 16 + ln] = (short)f2bf(p);
        }
      const short8 ap0 = *(const short8*)&Pw[ln * 72 + quad * 8];
      const short8 ap1 = *(const short8*)&Pw[ln * 72 + 32 + quad * 8];
#pragma unroll
      for (int dt = 0; dt < 4; dt++) {
        oA[dt] = MFMA16(ap0, bv0[dt], oA[dt]);
        oA[dt] = MFMA16(ap1, bv1[dt], oA[dt]);
      }
    }
  }

  // reduce per-lane l partials across the quad's 16 lanes
#pragma unroll
  for (int off = 1; off < 16; off <<= 1)
#pragma unroll
    for (int r = 0; r < 4; r++) {
      lsA[r] += __shfl_xor(lsA[r], off, 64);
      lsB[r] += __shfl_xor(lsB[r], off, 64);
    }

#pragma unroll
  for (int r = 0; r < 4; r++) {
    const float invA = 1.0f / lsA[r];
    const float invB = 1.0f / lsB[r];
    const int rowA = jA * 64 + w * 16 + quad * 4 + r;
    const int rowB = jB * 64 + w * 16 + quad * 4 + r;
#pragma unroll
    for (int dt = 0; dt < 4; dt++) {
      ctx[((size_t)(b * 2048 + rowA)) * 1024 + h * 64 + dt * 16 + ln] =
          f2bf(oA[dt][r] * invA);
      ctx[((size_t)(b * 2048 + rowB)) * 1024 + h * 64 + dt * 16 + ln] =
          f2bf(oB[dt][r] * invB);
    }
  }
}

// ---------------------------------------------------------------------------
// Workspace: [xb 8MB][w bf16 8MB][qb 8MB][kb 8MB][vtb 8MB][ctx 8MB]
// ---------------------------------------------------------------------------
extern "C" void kernel_launch(void* const* d_in, const int* in_sizes, int n_in,
                              void* d_out, int out_size, void* d_ws, size_t ws_size,
                              hipStream_t stream) {
  const float* x  = (const float*)d_in[0];
  const float* Wq = (const float*)d_in[1];
  const float* Wk = (const float*)d_in[2];
  const float* Wv = (const float*)d_in[3];
  const float* Wo = (const float*)d_in[4];
  float* out = (float*)d_out;
  char* ws = (char*)d_ws;

  ushort* xb  = (ushort*)(ws);
  ushort* wqb = (ushort*)(ws + (size_t)(8  << 20));
  ushort* qb  = (ushort*)(ws + (size_t)(16 << 20));
  ushort* kb  = (ushort*)(ws + (size_t)(24 << 20));
  ushort* vtb = (ushort*)(ws + (size_t)(32 << 20));
  ushort* ctx = (ushort*)(ws + (size_t)(40 << 20));

  cvt_all<<<8192, 256, 0, stream>>>(x, Wq, Wk, Wv, Wo, xb);
  gemm_bt<0, 64><<<dim3(48, 32), 256, 0, stream>>>(xb, wqb, (void*)qb, 1024);
  attnk<<<dim3(16, 32), 256, 0, stream>>>(qb, kb, vtb, ctx);
  gemm_bt<2, 64><<<dim3(16, 32), 256, 0, stream>>>(ctx, wqb + 3145728 /*wob*/, (void*)out, 1024);
}

// Round 11
// 191.732 us; speedup vs baseline: 1.0615x; 1.0615x over previous
//
#include <hip/hip_runtime.h>

// ---------------------------------------------------------------------------
// CovariateAttention: out = MHA_causal(rope(x@Wq^T), rope(x@Wk^T), x@Wv^T) @ Wo^T
// B=2, S=2048, E=d_attn=1024, H=16, hd=64. All GEMM-shaped work in bf16 MFMA.
// 4 launches: cvt -> gemm0(QKV + fused RoPE, BN=64) -> attnk -> gemm2(BM=64).
// ---------------------------------------------------------------------------

typedef float  f32x4  __attribute__((ext_vector_type(4)));
typedef short  short8 __attribute__((ext_vector_type(8)));

#define MFMA16(a,b,c) __builtin_amdgcn_mfma_f32_16x16x32_bf16((a),(b),(c),0,0,0)
// async global->LDS DMA, 16B/lane; LDS dest = wave-uniform base + lane*16
#define GLD_LDS16(g, l)                                                        \
  __builtin_amdgcn_global_load_lds(                                            \
      (const __attribute__((address_space(1))) unsigned int*)(g),              \
      (__attribute__((address_space(3))) unsigned int*)(l), 16, 0, 0)

__device__ __forceinline__ unsigned short f2bf(float f) {
  unsigned int x = __float_as_uint(f);
  x += 0x7fffu + ((x >> 16) & 1u);          // RNE
  return (unsigned short)(x >> 16);
}
__device__ __forceinline__ float bf2f(unsigned short u) {
  return __uint_as_float(((unsigned int)u) << 16);
}

// ---------------------------------------------------------------------------
// Kernel 1: convert x (4M fp32) + Wq,Wk,Wv,Wo (1M each) to bf16 (contiguous).
// (Inline-converting inside gemm0 would double A-fetch bytes through L2 —
// worse than this one 48MB HBM pass.)
// ---------------------------------------------------------------------------
__global__ __launch_bounds__(256) void cvt_all(const float* __restrict__ x,
                                               const float* __restrict__ wq,
                                               const float* __restrict__ wk,
                                               const float* __restrict__ wv,
                                               const float* __restrict__ wo,
                                               ushort* __restrict__ dst) {
  const int i = blockIdx.x * 256 + threadIdx.x;      // [0, 2M)
  const float* src;
  int off;
  if (i < 1048576) { src = x; off = i; }
  else {
    const int j = i - 1048576;
    const int wsel = j >> 18;
    off = j & 262143;
    src = (wsel == 0) ? wq : (wsel == 1) ? wk : (wsel == 2) ? wv : wo;
  }
  const float4 v = ((const float4*)src)[off];
  ushort4 o = make_ushort4(f2bf(v.x), f2bf(v.y), f2bf(v.z), f2bf(v.w));
  ((ushort4*)dst)[i] = o;
}

// ---------------------------------------------------------------------------
// GEMM (r9 structure: m97 + BK=64 twin panels; dbuf REVERTED — r10 measured
// -10us): C[m,n] = sum_k A[m,k]*B[n,k]. BM x BN tile, 256 thr = 4 waves (2x2),
// wave tile (BM/2) x (BN/2). BK=64 staged as TWO stride-32 panels via
// global_load_lds width=16; unpadded LDS stride 32; 2-barrier K-loop.
// MODE 0 (BM=128, BN=64): fused QKV, N=3072, 1536 blocks = 6/CU. Q/K get RoPE
//   in the epilogue (pair partner d^1 in adjacent lane -> __shfl_xor(.,1);
//   hw sincos, revolutions). Q scaled by attn_scale*log2e. V -> [bh][d][s].
// MODE 2 (BM=64, BN=64): fp32 out-proj, 1024 blocks = 4/CU (was 2/CU at
//   BM=128 — latency-bound, more resident blocks is the lever that has
//   reproducibly paid at this shape). acc VGPR 64->16.
// ---------------------------------------------------------------------------
template<int MODE, int BN, int BM>
__global__ __launch_bounds__(256) void gemm_bt(const ushort* __restrict__ A,
                                               const ushort* __restrict__ B,
                                               void* __restrict__ Cv,
                                               int K) {
  constexpr int NI = BN / 32;               // n-frags per wave
  constexpr int MI = BM / 32;               // m-frags per wave
  constexpr int AI = BM / 64;               // A staging instrs per wave/panel
  constexpr int BI = BN / 64;               // B staging instrs per wave/panel
  __shared__ __align__(16) short As0[BM * 32];
  __shared__ __align__(16) short As1[BM * 32];
  __shared__ __align__(16) short Bs0[BN * 32];
  __shared__ __align__(16) short Bs1[BN * 32];
  const int tid  = threadIdx.x;
  const int lane = tid & 63, w = tid >> 6;
  const int ln   = lane & 15, quad = lane >> 4;
  const int wm   = w >> 1, wn = w & 1;
  const int m0 = blockIdx.y * BM, n0 = blockIdx.x * BN;

  const int srow = lane >> 2;               // 0..15
  const int schk = (lane & 3) * 8;          // 0,8,16,24 (shorts)
  const int arow = w * (16 * AI);
  const int brow = w * (16 * BI);
  const ushort* Ag0 = A + (size_t)(m0 + arow + srow) * K + schk;
  const ushort* Ag1 = A + (size_t)(m0 + arow + 16 + srow) * K + schk; // AI==2
  const ushort* Bg0 = B + (size_t)(n0 + brow + srow) * K + schk;
  const ushort* Bg1 = B + (size_t)(n0 + brow + 16 + srow) * K + schk; // BI==2
  const int lA0 = arow * 32, lA1 = (arow + 16) * 32;
  const int lB0 = brow * 32, lB1 = (brow + 16) * 32;

  int aoff[MI], boff[NI];
#pragma unroll
  for (int i = 0; i < MI; i++)
    aoff[i] = (wm * (BM / 2) + i * 16 + ln) * 32 + quad * 8;
#pragma unroll
  for (int i = 0; i < NI; i++)
    boff[i] = (wn * (BN / 2) + i * 16 + ln) * 32 + quad * 8;
  f32x4 acc[MI][NI] = {};

  for (int kt = 0; kt < K; kt += 64) {
    __syncthreads();                        // WAR: prev rounds' reads done
    GLD_LDS16(Ag0 + kt, As0 + lA0);
    if (AI == 2) GLD_LDS16(Ag1 + kt, As0 + lA1);
    GLD_LDS16(Ag0 + kt + 32, As1 + lA0);
    if (AI == 2) GLD_LDS16(Ag1 + kt + 32, As1 + lA1);
    GLD_LDS16(Bg0 + kt, Bs0 + lB0);
    if (BI == 2) GLD_LDS16(Bg1 + kt, Bs0 + lB1);
    GLD_LDS16(Bg0 + kt + 32, Bs1 + lB0);
    if (BI == 2) GLD_LDS16(Bg1 + kt + 32, Bs1 + lB1);
    __syncthreads();                        // RAW: vmcnt drained at barrier
#pragma unroll
    for (int h = 0; h < 2; ++h) {
      const short* Ap = h ? As1 : As0;
      const short* Bp = h ? Bs1 : Bs0;
      short8 av[MI], bv[NI];
#pragma unroll
      for (int i = 0; i < MI; i++) av[i] = *(const short8*)&Ap[aoff[i]];
#pragma unroll
      for (int i = 0; i < NI; i++) bv[i] = *(const short8*)&Bp[boff[i]];
#pragma unroll
      for (int mi = 0; mi < MI; mi++)
#pragma unroll
        for (int ni = 0; ni < NI; ni++)
          acc[mi][ni] = MFMA16(av[mi], bv[ni], acc[mi][ni]);
    }
  }

  // Epilogue. C-layout: row = quad*4 + r, col = ln (verified m89/m91).
  if (MODE == 0) {
    ushort* Cq = (ushort*)Cv;
    if (n0 < 2048) {
      // ---- Q/K with fused RoPE ----
      ushort* dst = Cq + (n0 < 1024 ? 0 : 4194304);   // q or k buffer
      const int nbase = (n0 < 1024) ? n0 : n0 - 1024;
      const float qsc = (n0 < 1024) ? 0.04508422002778011f : 1.0f; // (1/32)*log2e
      const float sgn = (ln & 1) ? 1.0f : -1.0f;       // odd lane: +other*sn
      float invc[NI];                                  // invf * 1/(2*pi)
#pragma unroll
      for (int ni = 0; ni < NI; ni++) {
        // pair index within the head = (col & 63) >> 1, BN-generic
        const int ii = ((wn * (BN / 2) + ni * 16 + ln) & 63) >> 1;
        invc[ni] = __builtin_amdgcn_exp2f(-(float)ii * 0.4152410118579865f) *
                   0.15915494309189535f;
      }
#pragma unroll
      for (int mi = 0; mi < MI; mi++) {
        const int row = m0 + wm * (BM / 2) + mi * 16 + quad * 4;
#pragma unroll
        for (int ni = 0; ni < NI; ni++) {
          const int col = nbase + wn * (BN / 2) + ni * 16 + ln;
#pragma unroll
          for (int r = 0; r < 4; r++) {
            const float mine  = acc[mi][ni][r];
            const float other = __shfl_xor(mine, 1, 64);
            const int   s     = (row + r) & 2047;      // sequence position
            const float rev   = (float)s * invc[ni];
            const float rr    = rev - floorf(rev);
            const float sn = __builtin_amdgcn_sinf(rr);
            const float cs = __builtin_amdgcn_cosf(rr);
            const float rot = (mine * cs + sgn * other * sn) * qsc;
            dst[(size_t)(row + r) * 1024 + col] = f2bf(rot);
          }
        }
      }
    } else {
      // ---- V pre-transposed to [bh][d][s] (no rope) ----
      ushort* vt = Cq + 8388608;
#pragma unroll
      for (int mi = 0; mi < MI; mi++) {
        const int sm = m0 + wm * (BM / 2) + mi * 16 + quad * 4;  // token index
        const int b = sm >> 11, s = sm & 2047;
#pragma unroll
        for (int ni = 0; ni < NI; ni++) {
          const int nv = (n0 - 2048) + wn * (BN / 2) + ni * 16 + ln;
          const int bh = b * 16 + (nv >> 6), d = nv & 63;
          ushort4 u = make_ushort4(f2bf(acc[mi][ni][0]), f2bf(acc[mi][ni][1]),
                                   f2bf(acc[mi][ni][2]), f2bf(acc[mi][ni][3]));
          *(ushort4*)&vt[((size_t)bh * 64 + d) * 2048 + s] = u;
        }
      }
    }
  } else {
    float* C = (float*)Cv;
#pragma unroll
    for (int mi = 0; mi < MI; mi++) {
      const int row = m0 + wm * (BM / 2) + mi * 16 + quad * 4;
#pragma unroll
      for (int ni = 0; ni < NI; ni++) {
        const int col = n0 + wn * (BN / 2) + ni * 16 + ln;
#pragma unroll
        for (int r = 0; r < 4; r++)
          C[(size_t)(row + r) * 1024 + col] = acc[mi][ni][r];
      }
    }
  }
}

// ---------------------------------------------------------------------------
// Kernel 4 (r4-exact, measured 54.4-61.5us): causal-balanced flash attention,
// max-free softmax. Block x in [0,16) owns q-tiles jA=x (KV 0..x) and
// jB=31-x (KV 0..31-x): 33 tile-equivs, uniform. 256 thr = 4 waves; wave w
// owns rows [16w,16w+16) of each q-tile. Scores s' = qk*attn_scale*log2e are
// bounded (|s'|<~2.5) -> p=exp2(s') direct, no running max, no rescale;
// l as per-lane partials reduced once at the end. VGPR~100 (NO launch-bounds
// pin, NO 2-tile rounds, NO split-KV — rounds 5/6/7 all regressed or were
// neutral when perturbing this). LDS 27648 B.
// ---------------------------------------------------------------------------
__global__ __launch_bounds__(256) void attnk(const ushort* __restrict__ q,
                                             const ushort* __restrict__ k,
                                             const ushort* __restrict__ vt,
                                             ushort* __restrict__ ctx) {
  __shared__ __align__(16) short Ks[64 * 72];
  __shared__ __align__(16) short Vs[64 * 72];
  __shared__ __align__(16) short Ps[4 * 16 * 72];
  const int tid  = threadIdx.x;
  const int lane = tid & 63, w = tid >> 6;
  const int ln   = lane & 15, quad = lane >> 4;
  const int x = blockIdx.x, bh = blockIdx.y;
  const int b = bh >> 4, h = bh & 15;
  const int jA = x, jB = 31 - x;
  short* Pw = Ps + w * 1152;

  // Q fragments (A-layout: m=ln, k=quad*8+j)
  const size_t qbA = ((size_t)(b * 2048 + jA * 64 + w * 16 + ln)) * 1024 + h * 64;
  const size_t qbB = ((size_t)(b * 2048 + jB * 64 + w * 16 + ln)) * 1024 + h * 64;
  const short8 aqA0 = *(const short8*)&q[qbA + quad * 8];
  const short8 aqA1 = *(const short8*)&q[qbA + 32 + quad * 8];
  const short8 aqB0 = *(const short8*)&q[qbB + quad * 8];
  const short8 aqB1 = *(const short8*)&q[qbB + 32 + quad * 8];

  f32x4 oA[4] = {}, oB[4] = {};
  float lsA[4] = {0.f, 0.f, 0.f, 0.f}, lsB[4] = {0.f, 0.f, 0.f, 0.f};

  // staging: 256 threads cover 64x64 tile as 512 short8 slots
  const int s0 = tid, s1 = tid + 256;
  const int r0 = s0 >> 3, c0 = (s0 & 7) * 8;
  const int r1 = s1 >> 3, c1 = (s1 & 7) * 8;
  const ushort* kg0 = k  + ((size_t)(b * 2048 + r0)) * 1024 + h * 64 + c0;
  const ushort* kg1 = k  + ((size_t)(b * 2048 + r1)) * 1024 + h * 64 + c1;
  const ushort* vg0 = vt + ((size_t)(bh * 64 + r0)) * 2048 + c0;
  const ushort* vg1 = vt + ((size_t)(bh * 64 + r1)) * 2048 + c1;
  const int wK0 = r0 * 72 + c0, wK1 = r1 * 72 + c1;

  for (int t = 0; t <= jB; t++) {
    __syncthreads();                      // WAR vs previous compute
    *(short8*)&Ks[wK0] = *(const short8*)(kg0 + (size_t)t * 65536);
    *(short8*)&Ks[wK1] = *(const short8*)(kg1 + (size_t)t * 65536);
    *(short8*)&Vs[wK0] = *(const short8*)(vg0 + t * 64);
    *(short8*)&Vs[wK1] = *(const short8*)(vg1 + t * 64);
    __syncthreads();                      // RAW

    const bool actA = (t <= jA);          // block-uniform
    f32x4 scA[4], scB[4];
#pragma unroll
    for (int ct = 0; ct < 4; ct++) {
      const short8 bk0 = *(const short8*)&Ks[(ct * 16 + ln) * 72 + quad * 8];
      const short8 bk1 = *(const short8*)&Ks[(ct * 16 + ln) * 72 + 32 + quad * 8];
      f32x4 z = {0.f, 0.f, 0.f, 0.f};
      z = MFMA16(aqB0, bk0, z);
      z = MFMA16(aqB1, bk1, z);
      scB[ct] = z;
      if (actA) {
        f32x4 y = {0.f, 0.f, 0.f, 0.f};
        y = MFMA16(aqA0, bk0, y);
        y = MFMA16(aqA1, bk1, y);
        scA[ct] = y;
      }
    }
    if (t == jB) {                        // diag mask for tile B
#pragma unroll
      for (int ct = 0; ct < 4; ct++) {
        const int kv = (t << 6) + ct * 16 + ln;
#pragma unroll
        for (int r = 0; r < 4; r++)
          if (kv > jB * 64 + w * 16 + quad * 4 + r) scB[ct][r] = -100000.0f;
      }
    }
    if (actA && t == jA) {                // diag mask for tile A
#pragma unroll
      for (int ct = 0; ct < 4; ct++) {
        const int kv = (t << 6) + ct * 16 + ln;
#pragma unroll
        for (int r = 0; r < 4; r++)
          if (kv > jA * 64 + w * 16 + quad * 4 + r) scA[ct][r] = -100000.0f;
      }
    }

    // V fragments once, shared by both q-tiles
    short8 bv0[4], bv1[4];
#pragma unroll
    for (int dt = 0; dt < 4; dt++) {
      bv0[dt] = *(const short8*)&Vs[(dt * 16 + ln) * 72 + quad * 8];
      bv1[dt] = *(const short8*)&Vs[(dt * 16 + ln) * 72 + 32 + quad * 8];
    }

    // ---- tile B: p = exp2(s'), accumulate directly (no rescale) ----
#pragma unroll
    for (int ct = 0; ct < 4; ct++)
#pragma unroll
      for (int r = 0; r < 4; r++) {
        const float p = __builtin_amdgcn_exp2f(scB[ct][r]);
        lsB[r] += p;
        Pw[(quad * 4 + r) * 72 + ct * 16 + ln] = (short)f2bf(p);
      }
    {
      const short8 ap0 = *(const short8*)&Pw[ln * 72 + quad * 8];
      const short8 ap1 = *(const short8*)&Pw[ln * 72 + 32 + quad * 8];
#pragma unroll
      for (int dt = 0; dt < 4; dt++) {
        oB[dt] = MFMA16(ap0, bv0[dt], oB[dt]);
        oB[dt] = MFMA16(ap1, bv1[dt], oB[dt]);
      }
    }
    // ---- tile A (reuses Pw; same-wave LDS ops are ordered) ----
    if (actA) {
#pragma unroll
      for (int ct = 0; ct < 4; ct++)
#pragma unroll
        for (int r = 0; r < 4; r++) {
          const float p = __builtin_amdgcn_exp2f(scA[ct][r]);
          lsA[r] += p;
          Pw[(quad * 4 + r) * 72 + ct * 16 + ln] = (short)f2bf(p);
        }
      const short8 ap0 = *(const short8*)&Pw[ln * 72 + quad * 8];
      const short8 ap1 = *(const short8*)&Pw[ln * 72 + 32 + quad * 8];
#pragma unroll
      for (int dt = 0; dt < 4; dt++) {
        oA[dt] = MFMA16(ap0, bv0[dt], oA[dt]);
        oA[dt] = MFMA16(ap1, bv1[dt], oA[dt]);
      }
    }
  }

  // reduce per-lane l partials across the quad's 16 lanes
#pragma unroll
  for (int off = 1; off < 16; off <<= 1)
#pragma unroll
    for (int r = 0; r < 4; r++) {
      lsA[r] += __shfl_xor(lsA[r], off, 64);
      lsB[r] += __shfl_xor(lsB[r], off, 64);
    }

#pragma unroll
  for (int r = 0; r < 4; r++) {
    const float invA = 1.0f / lsA[r];
    const float invB = 1.0f / lsB[r];
    const int rowA = jA * 64 + w * 16 + quad * 4 + r;
    const int rowB = jB * 64 + w * 16 + quad * 4 + r;
#pragma unroll
    for (int dt = 0; dt < 4; dt++) {
      ctx[((size_t)(b * 2048 + rowA)) * 1024 + h * 64 + dt * 16 + ln] =
          f2bf(oA[dt][r] * invA);
      ctx[((size_t)(b * 2048 + rowB)) * 1024 + h * 64 + dt * 16 + ln] =
          f2bf(oB[dt][r] * invB);
    }
  }
}

// ---------------------------------------------------------------------------
// Workspace: [xb 8MB][w bf16 8MB][qb 8MB][kb 8MB][vtb 8MB][ctx 8MB]
// ---------------------------------------------------------------------------
extern "C" void kernel_launch(void* const* d_in, const int* in_sizes, int n_in,
                              void* d_out, int out_size, void* d_ws, size_t ws_size,
                              hipStream_t stream) {
  const float* x  = (const float*)d_in[0];
  const float* Wq = (const float*)d_in[1];
  const float* Wk = (const float*)d_in[2];
  const float* Wv = (const float*)d_in[3];
  const float* Wo = (const float*)d_in[4];
  float* out = (float*)d_out;
  char* ws = (char*)d_ws;

  ushort* xb  = (ushort*)(ws);
  ushort* wqb = (ushort*)(ws + (size_t)(8  << 20));
  ushort* qb  = (ushort*)(ws + (size_t)(16 << 20));
  ushort* kb  = (ushort*)(ws + (size_t)(24 << 20));
  ushort* vtb = (ushort*)(ws + (size_t)(32 << 20));
  ushort* ctx = (ushort*)(ws + (size_t)(40 << 20));

  cvt_all<<<8192, 256, 0, stream>>>(x, Wq, Wk, Wv, Wo, xb);
  gemm_bt<0, 64, 128><<<dim3(48, 32), 256, 0, stream>>>(xb, wqb, (void*)qb, 1024);
  attnk<<<dim3(16, 32), 256, 0, stream>>>(qb, kb, vtb, ctx);
  gemm_bt<2, 64, 64><<<dim3(16, 64), 256, 0, stream>>>(ctx, wqb + 3145728 /*wob*/, (void*)out, 1024);
}